// Round 3
// baseline (118.599 us; speedup 1.0000x reference)
//
#include <hip/hip_runtime.h>

typedef __attribute__((ext_vector_type(4))) int int4v;

constexpr int Mdim = 32768;   // 8*4096
constexpr int Kdim = 1024;
constexpr int Ndim = 1024;
constexpr float FEPS = 1e-8f;

// ---------------- ws layout (bytes) ----------------
// 0      : float scalars[8]  {gamma_w, gamma_b, scale, sg, qs, inv_scale}
// 1024   : float partials[256]   (|W| partial sums)
// 4096   : unsigned pmax[2048]   (per-block |x| max bits)
// 16384  : float bq[1024]
// 32768  : int8 wq (1 MB)  -- TILED: tile t=(nb*16+kt) is 1KB; lane l's 16B at t*1024+l*16
//                             holds W[nb*16 + (l&15)][kt*64 + (l>>4)*16 .. +15]
// +1MB   : int8 xq (32 MB) -- same tiling over rows of x
constexpr size_t WQ_OFF = 32768;
constexpr size_t XQ_OFF = WQ_OFF + (size_t)Ndim * Kdim;
constexpr size_t WS_NEED = XQ_OFF + (size_t)Mdim * Kdim;

// ---------------- pass 1: |x| absmax -> per-block slot (no atomics) ----------
__global__ void k_absmax(const uint4* __restrict__ xv, unsigned* __restrict__ pmax, int n4) {
  int i0 = blockIdx.x * blockDim.x + threadIdx.x;
  int stride = gridDim.x * blockDim.x;
  unsigned m = 0u;
  for (int i = i0; i < n4; i += stride) {
    uint4 v = xv[i];
    m = max(m, v.x & 0x7fffffffu);
    m = max(m, v.y & 0x7fffffffu);
    m = max(m, v.z & 0x7fffffffu);
    m = max(m, v.w & 0x7fffffffu);
  }
  #pragma unroll
  for (int off = 32; off > 0; off >>= 1)
    m = max(m, (unsigned)__shfl_down((int)m, off, 64));
  __shared__ unsigned red[4];
  if ((threadIdx.x & 63) == 0) red[threadIdx.x >> 6] = m;
  __syncthreads();
  if (threadIdx.x == 0) {
    unsigned r = max(max(red[0], red[1]), max(red[2], red[3]));
    pmax[blockIdx.x] = r;   // plain store, fixed slot: deterministic
  }
}

// ---------------- pass 2: per-block partial sums of |W| (fixed slots) --------
__global__ void k_wsum(const float4* __restrict__ wv, float* __restrict__ partials, int n4) {
  float s = 0.f;
  int stride = gridDim.x * blockDim.x;
  for (int i = blockIdx.x * blockDim.x + threadIdx.x; i < n4; i += stride) {
    float4 v = wv[i];
    s += fabsf(v.x) + fabsf(v.y) + fabsf(v.z) + fabsf(v.w);
  }
  __shared__ float red[256];
  red[threadIdx.x] = s;
  __syncthreads();
  for (int h = 128; h > 0; h >>= 1) {
    if (threadIdx.x < h) red[threadIdx.x] += red[threadIdx.x + h];
    __syncthreads();
  }
  if (threadIdx.x == 0) partials[blockIdx.x] = red[0];
}

// ---------------- pass 3: scalars + quantized bias --------------------------
__global__ void k_finalize(const float* __restrict__ bias, const float* __restrict__ partials,
                           const unsigned* __restrict__ pmax,
                           float* __restrict__ scalars, float* __restrict__ bq) {
  __shared__ float redf[256];
  __shared__ unsigned redu[256];
  __shared__ float sh_gb;
  int t = threadIdx.x;

  float s = fabsf(bias[t]) + fabsf(bias[t + 256]) + fabsf(bias[t + 512]) + fabsf(bias[t + 768]);
  redf[t] = s;
  unsigned m = 0u;
  #pragma unroll
  for (int i = 0; i < 8; ++i) m = max(m, pmax[t + 256 * i]);
  redu[t] = m;
  __syncthreads();
  for (int h = 128; h > 0; h >>= 1) {
    if (t < h) {
      redf[t] += redf[t + h];
      redu[t] = max(redu[t], redu[t + h]);
    }
    __syncthreads();
  }
  if (t == 0) {
    float gb = redf[0] / 1024.0f;
    float sw = 0.f;
    for (int i = 0; i < 256; ++i) sw += partials[i];
    float gw = sw / (1024.0f * 1024.0f);
    float maxval = __uint_as_float(redu[0]);
    float v = maxval / 127.0f + FEPS;
    int e = (int)((__float_as_uint(v) >> 23) & 0xff) - 127;
    float scale = ldexpf(1.0f, e);
    scalars[0] = gw;
    scalars[1] = gb;
    scalars[2] = scale;
    scalars[3] = scale * gw;       // epilogue multiplier
    scalars[4] = 127.0f * scale;   // clip bound (exact)
    scalars[5] = ldexpf(1.0f, -e); // inv_scale (exact power of 2)
    sh_gb = gb;
  }
  __syncthreads();
  float gb = sh_gb;
  for (int i = t; i < 1024; i += 256) {
    float q = rintf(bias[i] / (gb + FEPS));
    q = fminf(fmaxf(q, -1.0f), 1.0f);
    bq[i] = q * gb;
  }
}

// ---------------- quant helpers ---------------------------------------------
__device__ __forceinline__ int qact8(float v, float qs, float inv) {
  return (int)rintf(fminf(fmaxf(v, -qs), qs) * inv);  // in [-127,127]
}

// ---------------- pass 4: ternary-quantize W into TILED int8 ----------------
// one wave per 1KB tile; lane l: r=l>>2 (row in 16-block), c=l&3 (16B k-chunk)
__global__ void k_wquant(const float* __restrict__ w, const float* __restrict__ scalars,
                         unsigned char* __restrict__ wq) {
  float inv_g = scalars[0] + FEPS;
  int wave = (blockIdx.x * blockDim.x + threadIdx.x) >> 6;  // tile index, 0..1023
  int lane = threadIdx.x & 63;
  int nb = wave >> 4;
  int kt = wave & 15;
  int r = lane >> 2;
  int c = lane & 3;
  const float4* src = (const float4*)(w + (size_t)(nb * 16 + r) * Kdim + kt * 64 + c * 16);
  unsigned o[4];
  #pragma unroll
  for (int v = 0; v < 4; ++v) {
    float4 f = src[v];
    int a = (int)rintf(fminf(fmaxf(f.x / inv_g, -1.f), 1.f));
    int b = (int)rintf(fminf(fmaxf(f.y / inv_g, -1.f), 1.f));
    int cc = (int)rintf(fminf(fmaxf(f.z / inv_g, -1.f), 1.f));
    int d = (int)rintf(fminf(fmaxf(f.w / inv_g, -1.f), 1.f));
    o[v] = (unsigned)(a & 0xff) | ((unsigned)(b & 0xff) << 8) |
           ((unsigned)(cc & 0xff) << 16) | ((unsigned)(d & 0xff) << 24);
  }
  uint4 pk; pk.x = o[0]; pk.y = o[1]; pk.z = o[2]; pk.w = o[3];
  *(uint4*)(wq + (size_t)wave * 1024 + c * 256 + r * 16) = pk;
}

// ---------------- pass 5: quantize x into TILED int8 ------------------------
__global__ void k_xquant(const float* __restrict__ x, const float* __restrict__ scalars,
                         unsigned char* __restrict__ xq) {
  float qs = scalars[4], inv = scalars[5];
  int wave = (blockIdx.x * blockDim.x + threadIdx.x) >> 6;  // tile index, 0..32767
  int lane = threadIdx.x & 63;
  int mb = wave >> 4;
  int kt = wave & 15;
  int r = lane >> 2;
  int c = lane & 3;
  const float4* src = (const float4*)(x + (size_t)(mb * 16 + r) * Kdim + kt * 64 + c * 16);
  unsigned o[4];
  #pragma unroll
  for (int v = 0; v < 4; ++v) {
    float4 f = src[v];
    o[v] = (unsigned)(qact8(f.x, qs, inv) & 0xff) |
           ((unsigned)(qact8(f.y, qs, inv) & 0xff) << 8) |
           ((unsigned)(qact8(f.z, qs, inv) & 0xff) << 16) |
           ((unsigned)(qact8(f.w, qs, inv) & 0xff) << 24);
  }
  uint4 pk; pk.x = o[0]; pk.y = o[1]; pk.z = o[2]; pk.w = o[3];
  *(uint4*)(xq + (size_t)wave * 1024 + c * 256 + r * 16) = pk;
}

// ---------------- pass 6: int8 MFMA GEMM, fragment-direct, NO LDS -----------
// C[m][n] = (sum_k xint[m][k]*t[n][k]) * sg + bq[n]   (i32 accum, exact)
// 128x128 tile per block, 4 waves 2x2, each wave 64x64 = 4x4 frags of 16x16x64.
// A/B fragments loaded straight from the tiled xq/wq: tile t -> 16B at t*1024+lane*16.
__launch_bounds__(256)
__global__ void k_gemm(const unsigned char* __restrict__ xq, const unsigned char* __restrict__ wq,
                       const float* __restrict__ scalars, const float* __restrict__ bq,
                       float* __restrict__ out) {
  const int tid = threadIdx.x;
  const int lane = tid & 63;
  const int wv = tid >> 6;          // 0..3
  const int wr = wv >> 1;           // wave row 0..1
  const int wc = wv & 1;            // wave col 0..1

  // XCD-aware swizzle (2048 % 8 == 0 -> bijective); consecutive same-XCD blocks
  // share the A row-panel (ntile varies fastest) for L2 locality.
  int bid = blockIdx.x;
  int swz = (bid & 7) * ((int)gridDim.x >> 3) + (bid >> 3);
  const int mtile = swz >> 3;       // 0..255
  const int ntile = swz & 7;        // 0..7
  const int m0 = mtile * 128;
  const int n0 = ntile * 128;

  // fragment tile bases: A tile index = mb*16 + kt, each 1KB
  const unsigned char* Abase = xq + ((size_t)(m0 / 16 + wr * 4) * 16) * 1024 + lane * 16;
  const unsigned char* Bbase = wq + ((size_t)(n0 / 16 + wc * 4) * 16) * 1024 + lane * 16;
  // stride between consecutive mi tiles = 16*1024 bytes; between kt = 1024 bytes

  int4v acc[4][4];
  #pragma unroll
  for (int i = 0; i < 4; ++i)
    #pragma unroll
    for (int j = 0; j < 4; ++j)
      acc[i][j] = (int4v){0, 0, 0, 0};

  int4v a0[4], b0[4], a1[4], b1[4];

#define LOADF(abuf, bbuf, kt) do {                                            \
    _Pragma("unroll")                                                         \
    for (int mi = 0; mi < 4; ++mi)                                            \
      abuf[mi] = *(const int4v*)(Abase + ((size_t)mi * 16 + (kt)) * 1024);    \
    _Pragma("unroll")                                                         \
    for (int ni = 0; ni < 4; ++ni)                                            \
      bbuf[ni] = *(const int4v*)(Bbase + ((size_t)ni * 16 + (kt)) * 1024);    \
  } while (0)

#define MFMAS(abuf, bbuf) do {                                                \
    _Pragma("unroll")                                                         \
    for (int mi = 0; mi < 4; ++mi)                                            \
      _Pragma("unroll")                                                       \
      for (int ni = 0; ni < 4; ++ni)                                          \
        acc[mi][ni] = __builtin_amdgcn_mfma_i32_16x16x64_i8(abuf[mi], bbuf[ni], acc[mi][ni], 0, 0, 0); \
  } while (0)

  LOADF(a0, b0, 0);
  #pragma unroll
  for (int kt = 0; kt < 16; kt += 2) {
    if (kt + 1 < 16) LOADF(a1, b1, kt + 1);
    MFMAS(a0, b0);
    if (kt + 2 < 16) LOADF(a0, b0, kt + 2);
    MFMAS(a1, b1);
  }
#undef LOADF
#undef MFMAS

  // epilogue: exact i32 -> f32, scale, bias
  const float sg = scalars[3];
  const int fr = lane & 15;
  #pragma unroll
  for (int ni = 0; ni < 4; ++ni) {
    const int col = n0 + wc * 64 + ni * 16 + fr;
    const float bb = bq[col];
    #pragma unroll
    for (int mi = 0; mi < 4; ++mi) {
      const int rowb = m0 + wr * 64 + mi * 16 + (lane >> 4) * 4;
      #pragma unroll
      for (int r = 0; r < 4; ++r)
        out[(size_t)(rowb + r) * Ndim + col] = (float)acc[mi][ni][r] * sg + bb;
    }
  }
}

extern "C" void kernel_launch(void* const* d_in, const int* in_sizes, int n_in,
                              void* d_out, int out_size, void* d_ws, size_t ws_size,
                              hipStream_t stream) {
  const float* x = (const float*)d_in[0];
  const float* weight = (const float*)d_in[1];
  const float* bias = (const float*)d_in[2];
  float* out = (float*)d_out;

  if (ws_size < WS_NEED) return;

  char* ws = (char*)d_ws;
  float* scalars = (float*)ws;
  float* partials = (float*)(ws + 1024);
  unsigned* pmax = (unsigned*)(ws + 4096);
  float* bq = (float*)(ws + 16384);
  unsigned char* wq = (unsigned char*)(ws + WQ_OFF);
  unsigned char* xq = (unsigned char*)(ws + XQ_OFF);

  k_absmax<<<2048, 256, 0, stream>>>((const uint4*)x, pmax, Mdim * Kdim / 4);
  k_wsum<<<256, 256, 0, stream>>>((const float4*)weight, partials, Ndim * Kdim / 4);
  k_finalize<<<1, 256, 0, stream>>>(bias, partials, pmax, scalars, bq);
  k_wquant<<<256, 256, 0, stream>>>(weight, scalars, wq);      // 1024 tiles, 1 wave each
  k_xquant<<<8192, 256, 0, stream>>>(x, scalars, xq);          // 32768 tiles, 1 wave each
  k_gemm<<<2048, 256, 0, stream>>>(xq, wq, scalars, bq, out);
}

// Round 4
// 112.173 us; speedup vs baseline: 1.0573x; 1.0573x over previous
//
#include <hip/hip_runtime.h>

typedef __attribute__((ext_vector_type(4))) int int4v;

constexpr int Mdim = 32768;   // 8*4096
constexpr int Kdim = 1024;
constexpr int Ndim = 1024;
constexpr float FEPS = 1e-8f;

// ---------------- ws layout (bytes) ----------------
// 0      : float scalars[8]  {gamma_w, gamma_b, scale, sg, qs, inv_scale}
// 1024   : float partials[256]   (|W| partial sums)
// 4096   : unsigned pmax[2048]   (per-block |x| max bits)
// 16384  : float bq[1024]
// 32768  : int8 wq (1 MB)  -- TILED: tile t=(nb*16+kt) is 1KB; lane l's 16B at t*1024+l*16
//                             holds W[nb*16 + (l&15)][kt*64 + (l>>4)*16 .. +15]
// +1MB   : int8 xq (32 MB) -- same tiling over rows of x
constexpr size_t WQ_OFF = 32768;
constexpr size_t XQ_OFF = WQ_OFF + (size_t)Ndim * Kdim;
constexpr size_t WS_NEED = XQ_OFF + (size_t)Mdim * Kdim;

__device__ __forceinline__ void gload16(const void* g, void* l) {
  __builtin_amdgcn_global_load_lds(
      (const __attribute__((address_space(1))) unsigned int*)g,
      (__attribute__((address_space(3))) unsigned int*)l, 16, 0, 0);
}

// ---------------- pass 1: |x| absmax -> per-block slot (no atomics) ----------
__global__ void k_absmax(const uint4* __restrict__ xv, unsigned* __restrict__ pmax, int n4) {
  int i0 = blockIdx.x * blockDim.x + threadIdx.x;
  int stride = gridDim.x * blockDim.x;
  unsigned m = 0u;
  for (int i = i0; i < n4; i += stride) {
    uint4 v = xv[i];
    m = max(m, v.x & 0x7fffffffu);
    m = max(m, v.y & 0x7fffffffu);
    m = max(m, v.z & 0x7fffffffu);
    m = max(m, v.w & 0x7fffffffu);
  }
  #pragma unroll
  for (int off = 32; off > 0; off >>= 1)
    m = max(m, (unsigned)__shfl_down((int)m, off, 64));
  __shared__ unsigned red[4];
  if ((threadIdx.x & 63) == 0) red[threadIdx.x >> 6] = m;
  __syncthreads();
  if (threadIdx.x == 0) {
    unsigned r = max(max(red[0], red[1]), max(red[2], red[3]));
    pmax[blockIdx.x] = r;   // plain store, fixed slot: deterministic
  }
}

// ---------------- pass 2: per-block partial sums of |W| (fixed slots) --------
__global__ void k_wsum(const float4* __restrict__ wv, float* __restrict__ partials, int n4) {
  float s = 0.f;
  int stride = gridDim.x * blockDim.x;
  for (int i = blockIdx.x * blockDim.x + threadIdx.x; i < n4; i += stride) {
    float4 v = wv[i];
    s += fabsf(v.x) + fabsf(v.y) + fabsf(v.z) + fabsf(v.w);
  }
  __shared__ float red[256];
  red[threadIdx.x] = s;
  __syncthreads();
  for (int h = 128; h > 0; h >>= 1) {
    if (threadIdx.x < h) red[threadIdx.x] += red[threadIdx.x + h];
    __syncthreads();
  }
  if (threadIdx.x == 0) partials[blockIdx.x] = red[0];
}

// ---------------- pass 3: scalars + quantized bias --------------------------
__global__ void k_finalize(const float* __restrict__ bias, const float* __restrict__ partials,
                           const unsigned* __restrict__ pmax,
                           float* __restrict__ scalars, float* __restrict__ bq) {
  __shared__ float redf[256];
  __shared__ unsigned redu[256];
  __shared__ float sh_gb;
  int t = threadIdx.x;

  float s = fabsf(bias[t]) + fabsf(bias[t + 256]) + fabsf(bias[t + 512]) + fabsf(bias[t + 768]);
  redf[t] = s;
  unsigned m = 0u;
  #pragma unroll
  for (int i = 0; i < 8; ++i) m = max(m, pmax[t + 256 * i]);
  redu[t] = m;
  __syncthreads();
  for (int h = 128; h > 0; h >>= 1) {
    if (t < h) {
      redf[t] += redf[t + h];
      redu[t] = max(redu[t], redu[t + h]);
    }
    __syncthreads();
  }
  if (t == 0) {
    float gb = redf[0] / 1024.0f;
    float sw = 0.f;
    for (int i = 0; i < 256; ++i) sw += partials[i];
    float gw = sw / (1024.0f * 1024.0f);
    float maxval = __uint_as_float(redu[0]);
    float v = maxval / 127.0f + FEPS;
    int e = (int)((__float_as_uint(v) >> 23) & 0xff) - 127;
    float scale = ldexpf(1.0f, e);
    scalars[0] = gw;
    scalars[1] = gb;
    scalars[2] = scale;
    scalars[3] = scale * gw;       // epilogue multiplier
    scalars[4] = 127.0f * scale;   // clip bound (exact)
    scalars[5] = ldexpf(1.0f, -e); // inv_scale (exact power of 2)
    sh_gb = gb;
  }
  __syncthreads();
  float gb = sh_gb;
  for (int i = t; i < 1024; i += 256) {
    float q = rintf(bias[i] / (gb + FEPS));
    q = fminf(fmaxf(q, -1.0f), 1.0f);
    bq[i] = q * gb;
  }
}

// ---------------- quant helpers ---------------------------------------------
__device__ __forceinline__ int qact8(float v, float qs, float inv) {
  return (int)rintf(fminf(fmaxf(v, -qs), qs) * inv);  // in [-127,127]
}

// ---------------- pass 4: ternary-quantize W into TILED int8 ----------------
__global__ void k_wquant(const float* __restrict__ w, const float* __restrict__ scalars,
                         unsigned char* __restrict__ wq) {
  float inv_g = scalars[0] + FEPS;
  int wave = (blockIdx.x * blockDim.x + threadIdx.x) >> 6;  // tile index, 0..1023
  int lane = threadIdx.x & 63;
  int nb = wave >> 4;
  int kt = wave & 15;
  int r = lane >> 2;
  int c = lane & 3;
  const float4* src = (const float4*)(w + (size_t)(nb * 16 + r) * Kdim + kt * 64 + c * 16);
  unsigned o[4];
  #pragma unroll
  for (int v = 0; v < 4; ++v) {
    float4 f = src[v];
    int a = (int)rintf(fminf(fmaxf(f.x / inv_g, -1.f), 1.f));
    int b = (int)rintf(fminf(fmaxf(f.y / inv_g, -1.f), 1.f));
    int cc = (int)rintf(fminf(fmaxf(f.z / inv_g, -1.f), 1.f));
    int d = (int)rintf(fminf(fmaxf(f.w / inv_g, -1.f), 1.f));
    o[v] = (unsigned)(a & 0xff) | ((unsigned)(b & 0xff) << 8) |
           ((unsigned)(cc & 0xff) << 16) | ((unsigned)(d & 0xff) << 24);
  }
  uint4 pk; pk.x = o[0]; pk.y = o[1]; pk.z = o[2]; pk.w = o[3];
  *(uint4*)(wq + (size_t)wave * 1024 + c * 256 + r * 16) = pk;
}

// ---------------- pass 5: quantize x into TILED int8 ------------------------
__global__ void k_xquant(const float* __restrict__ x, const float* __restrict__ scalars,
                         unsigned char* __restrict__ xq) {
  float qs = scalars[4], inv = scalars[5];
  int wave = (blockIdx.x * blockDim.x + threadIdx.x) >> 6;  // tile index, 0..32767
  int lane = threadIdx.x & 63;
  int mb = wave >> 4;
  int kt = wave & 15;
  int r = lane >> 2;
  int c = lane & 3;
  const float4* src = (const float4*)(x + (size_t)(mb * 16 + r) * Kdim + kt * 64 + c * 16);
  unsigned o[4];
  #pragma unroll
  for (int v = 0; v < 4; ++v) {
    float4 f = src[v];
    o[v] = (unsigned)(qact8(f.x, qs, inv) & 0xff) |
           ((unsigned)(qact8(f.y, qs, inv) & 0xff) << 8) |
           ((unsigned)(qact8(f.z, qs, inv) & 0xff) << 16) |
           ((unsigned)(qact8(f.w, qs, inv) & 0xff) << 24);
  }
  uint4 pk; pk.x = o[0]; pk.y = o[1]; pk.z = o[2]; pk.w = o[3];
  *(uint4*)(xq + (size_t)wave * 1024 + c * 256 + r * 16) = pk;
}

// ---------------- pass 6: int8 MFMA GEMM, LDS-staged, counted-vmcnt ---------
// 128x128 tile per block, 4 waves 2x2, BK=64 i8. 3 LDS buffers (16KB each):
// per step: vmcnt(4) -> raw barrier -> ds_read frags -> STAGE(kt+2) -> 16 MFMA.
// LDS layout == fragment layout (1KB tiles, lane*16), so staging is linear
// (global_load_lds-compatible) and ds_read_b128 is conflict-free.
__launch_bounds__(256)
__global__ void k_gemm(const unsigned char* __restrict__ xq, const unsigned char* __restrict__ wq,
                       const float* __restrict__ scalars, const float* __restrict__ bq,
                       float* __restrict__ out) {
  __shared__ __align__(16) unsigned char lds[3 * 16384];

  const int tid = threadIdx.x;
  const int lane = tid & 63;
  const int wv = tid >> 6;          // 0..3
  const int wr = wv >> 1;           // wave row 0..1
  const int wc = wv & 1;            // wave col 0..1

  // XCD-aware swizzle (2048 % 8 == 0 -> bijective); each XCD owns a contiguous
  // mtile range so A panels are L2-local.
  int bid = blockIdx.x;
  int swz = (bid & 7) * ((int)gridDim.x >> 3) + (bid >> 3);
  const int mtile = swz >> 3;       // 0..255
  const int ntile = swz & 7;        // 0..7
  const int m0 = mtile * 128;
  const int n0 = ntile * 128;

  // per-wave stage pointers: wave wv stages A tiles {wv, wv+4}, B tiles {wv, wv+4}
  const unsigned char* gA0 = xq + ((size_t)(mtile * 8 + wv) * 16) * 1024 + lane * 16;
  const unsigned char* gA1 = xq + ((size_t)(mtile * 8 + wv + 4) * 16) * 1024 + lane * 16;
  const unsigned char* gB0 = wq + ((size_t)(ntile * 8 + wv) * 16) * 1024 + lane * 16;
  const unsigned char* gB1 = wq + ((size_t)(ntile * 8 + wv + 4) * 16) * 1024 + lane * 16;
  const int lA0 = wv * 1024, lA1 = (wv + 4) * 1024;
  const int lB0 = 8192 + wv * 1024, lB1 = 8192 + (wv + 4) * 1024;

#define STAGE(kt, buf) do {                                   \
    unsigned char* base_ = lds + (buf) * 16384;               \
    gload16(gA0 + (size_t)(kt) * 1024, base_ + lA0);          \
    gload16(gA1 + (size_t)(kt) * 1024, base_ + lA1);          \
    gload16(gB0 + (size_t)(kt) * 1024, base_ + lB0);          \
    gload16(gB1 + (size_t)(kt) * 1024, base_ + lB1);          \
  } while (0)

  int4v acc[4][4];
  #pragma unroll
  for (int i = 0; i < 4; ++i)
    #pragma unroll
    for (int j = 0; j < 4; ++j)
      acc[i][j] = (int4v){0, 0, 0, 0};

  const int aoff = wr * 4 * 1024 + lane * 16;
  const int boff = 8192 + wc * 4 * 1024 + lane * 16;

  STAGE(0, 0);
  STAGE(1, 1);

  int cur = 0;
  for (int kt = 0; kt < 15; ++kt) {
    asm volatile("s_waitcnt vmcnt(4)" ::: "memory");  // stage(kt) landed
    __builtin_amdgcn_s_barrier();
    asm volatile("" ::: "memory");                    // pin mem ops below barrier
    const unsigned char* bufp = lds + cur * 16384;
    int4v a[4], b[4];
    #pragma unroll
    for (int mi = 0; mi < 4; ++mi)
      a[mi] = *(const int4v*)(bufp + aoff + mi * 1024);
    #pragma unroll
    for (int ni = 0; ni < 4; ++ni)
      b[ni] = *(const int4v*)(bufp + boff + ni * 1024);
    if (kt < 14) {
      int nb = cur + 2; if (nb >= 3) nb -= 3;
      STAGE(kt + 2, nb);                              // issued post-barrier: no race
    }
    #pragma unroll
    for (int mi = 0; mi < 4; ++mi)
      #pragma unroll
      for (int ni = 0; ni < 4; ++ni)
        acc[mi][ni] = __builtin_amdgcn_mfma_i32_16x16x64_i8(a[mi], b[ni], acc[mi][ni], 0, 0, 0);
    cur = (cur == 2) ? 0 : cur + 1;
  }
  // final step kt=15
  asm volatile("s_waitcnt vmcnt(0)" ::: "memory");
  __builtin_amdgcn_s_barrier();
  asm volatile("" ::: "memory");
  {
    const unsigned char* bufp = lds + cur * 16384;
    int4v a[4], b[4];
    #pragma unroll
    for (int mi = 0; mi < 4; ++mi)
      a[mi] = *(const int4v*)(bufp + aoff + mi * 1024);
    #pragma unroll
    for (int ni = 0; ni < 4; ++ni)
      b[ni] = *(const int4v*)(bufp + boff + ni * 1024);
    #pragma unroll
    for (int mi = 0; mi < 4; ++mi)
      #pragma unroll
      for (int ni = 0; ni < 4; ++ni)
        acc[mi][ni] = __builtin_amdgcn_mfma_i32_16x16x64_i8(a[mi], b[ni], acc[mi][ni], 0, 0, 0);
  }
#undef STAGE

  // epilogue: exact i32 -> f32, scale, bias
  const float sg = scalars[3];
  const int fr = lane & 15;
  #pragma unroll
  for (int ni = 0; ni < 4; ++ni) {
    const int col = n0 + wc * 64 + ni * 16 + fr;
    const float bb = bq[col];
    #pragma unroll
    for (int mi = 0; mi < 4; ++mi) {
      const int rowb = m0 + wr * 64 + mi * 16 + (lane >> 4) * 4;
      #pragma unroll
      for (int r = 0; r < 4; ++r)
        out[(size_t)(rowb + r) * Ndim + col] = (float)acc[mi][ni][r] * sg + bb;
    }
  }
}

extern "C" void kernel_launch(void* const* d_in, const int* in_sizes, int n_in,
                              void* d_out, int out_size, void* d_ws, size_t ws_size,
                              hipStream_t stream) {
  const float* x = (const float*)d_in[0];
  const float* weight = (const float*)d_in[1];
  const float* bias = (const float*)d_in[2];
  float* out = (float*)d_out;

  if (ws_size < WS_NEED) return;

  char* ws = (char*)d_ws;
  float* scalars = (float*)ws;
  float* partials = (float*)(ws + 1024);
  unsigned* pmax = (unsigned*)(ws + 4096);
  float* bq = (float*)(ws + 16384);
  unsigned char* wq = (unsigned char*)(ws + WQ_OFF);
  unsigned char* xq = (unsigned char*)(ws + XQ_OFF);

  k_absmax<<<2048, 256, 0, stream>>>((const uint4*)x, pmax, Mdim * Kdim / 4);
  k_wsum<<<256, 256, 0, stream>>>((const float4*)weight, partials, Ndim * Kdim / 4);
  k_finalize<<<1, 256, 0, stream>>>(bias, partials, pmax, scalars, bq);
  k_wquant<<<256, 256, 0, stream>>>(weight, scalars, wq);
  k_xquant<<<8192, 256, 0, stream>>>(x, scalars, xq);
  k_gemm<<<2048, 256, 0, stream>>>(xq, wq, scalars, bq, out);
}

// Round 5
// 103.119 us; speedup vs baseline: 1.1501x; 1.0878x over previous
//
#include <hip/hip_runtime.h>

typedef __attribute__((ext_vector_type(4))) int int4v;

constexpr int Mdim = 32768;   // 8*4096
constexpr int Kdim = 1024;
constexpr int Ndim = 1024;
constexpr float FEPS = 1e-8f;

// ---------------- ws layout (bytes) ----------------
// 0      : float scalars[8]  {gamma_w, gamma_b, scale, sg, qs, inv_scale}
// 1024   : float partials[256]   (|W| partial sums)
// 4096   : unsigned pmax[2048]   (per-block |x| max bits)
// 16384  : float bq[1024]
// 32768  : int8 wq (1 MB)  -- TILED: tile t=(nb*16+kt) is 1KB; byte l*16 of tile t
//                             holds W[nb*16 + (l&15)][kt*64 + (l>>4)*16 .. +15]
// +1MB   : int8 xq (32 MB) -- same tiling over rows of x
constexpr size_t WQ_OFF = 32768;
constexpr size_t XQ_OFF = WQ_OFF + (size_t)Ndim * Kdim;
constexpr size_t WS_NEED = XQ_OFF + (size_t)Mdim * Kdim;

__device__ __forceinline__ void gload16(const void* g, void* l) {
  __builtin_amdgcn_global_load_lds(
      (const __attribute__((address_space(1))) unsigned int*)g,
      (__attribute__((address_space(3))) unsigned int*)l, 16, 0, 0);
}

// ---------------- pass 1 (merged): |x| absmax partials + |W| sum partials ----
// blocks [0,2048): absmax of x -> pmax[b]; blocks [2048,2304): |W| sums -> partials[b-2048]
__global__ void k_pre(const uint4* __restrict__ xv, const float4* __restrict__ wv,
                      unsigned* __restrict__ pmax, float* __restrict__ partials) {
  const int tid = threadIdx.x;
  if (blockIdx.x < 2048) {
    int i0 = blockIdx.x * 256 + tid;
    const int stride = 2048 * 256;
    const int n4 = Mdim * Kdim / 4;
    unsigned m = 0u;
    for (int i = i0; i < n4; i += stride) {
      uint4 v = xv[i];
      m = max(m, v.x & 0x7fffffffu);
      m = max(m, v.y & 0x7fffffffu);
      m = max(m, v.z & 0x7fffffffu);
      m = max(m, v.w & 0x7fffffffu);
    }
    #pragma unroll
    for (int off = 32; off > 0; off >>= 1)
      m = max(m, (unsigned)__shfl_down((int)m, off, 64));
    __shared__ unsigned red[4];
    if ((tid & 63) == 0) red[tid >> 6] = m;
    __syncthreads();
    if (tid == 0)
      pmax[blockIdx.x] = max(max(red[0], red[1]), max(red[2], red[3]));
  } else {
    int wb = blockIdx.x - 2048;
    float s = 0.f;
    const int stride = 256 * 256;
    const int n4 = Ndim * Kdim / 4;
    for (int i = wb * 256 + tid; i < n4; i += stride) {
      float4 v = wv[i];
      s += fabsf(v.x) + fabsf(v.y) + fabsf(v.z) + fabsf(v.w);
    }
    __shared__ float red[256];
    red[tid] = s;
    __syncthreads();
    for (int h = 128; h > 0; h >>= 1) {
      if (tid < h) red[tid] += red[tid + h];
      __syncthreads();
    }
    if (tid == 0) partials[wb] = red[0];
  }
}

// ---------------- pass 2: scalars + quantized bias (bit-identical to r4) -----
__global__ void k_finalize(const float* __restrict__ bias, const float* __restrict__ partials,
                           const unsigned* __restrict__ pmax,
                           float* __restrict__ scalars, float* __restrict__ bq) {
  __shared__ float redf[256];
  __shared__ unsigned redu[256];
  __shared__ float sh_gb;
  int t = threadIdx.x;

  float s = fabsf(bias[t]) + fabsf(bias[t + 256]) + fabsf(bias[t + 512]) + fabsf(bias[t + 768]);
  redf[t] = s;
  unsigned m = 0u;
  #pragma unroll
  for (int i = 0; i < 8; ++i) m = max(m, pmax[t + 256 * i]);
  redu[t] = m;
  __syncthreads();
  for (int h = 128; h > 0; h >>= 1) {
    if (t < h) {
      redf[t] += redf[t + h];
      redu[t] = max(redu[t], redu[t + h]);
    }
    __syncthreads();
  }
  if (t == 0) {
    float gb = redf[0] / 1024.0f;
    float sw = 0.f;
    for (int i = 0; i < 256; ++i) sw += partials[i];
    float gw = sw / (1024.0f * 1024.0f);
    float maxval = __uint_as_float(redu[0]);
    float v = maxval / 127.0f + FEPS;
    int e = (int)((__float_as_uint(v) >> 23) & 0xff) - 127;
    float scale = ldexpf(1.0f, e);
    scalars[0] = gw;
    scalars[1] = gb;
    scalars[2] = scale;
    scalars[3] = scale * gw;       // epilogue multiplier
    scalars[4] = 127.0f * scale;   // clip bound (exact)
    scalars[5] = ldexpf(1.0f, -e); // inv_scale (exact power of 2)
    sh_gb = gb;
  }
  __syncthreads();
  float gb = sh_gb;
  for (int i = t; i < 1024; i += 256) {
    float q = rintf(bias[i] / (gb + FEPS));
    q = fminf(fmaxf(q, -1.0f), 1.0f);
    bq[i] = q * gb;
  }
}

// ---------------- quant helpers ---------------------------------------------
__device__ __forceinline__ int qact8(float v, float qs, float inv) {
  return (int)rintf(fminf(fmaxf(v, -qs), qs) * inv);  // in [-127,127]
}

// ---------------- pass 3 (merged): quantize x and W into TILED int8 ----------
// One wave per 1KB tile. Lane l: row r=l&15, k-chunk c=l>>4 -> write at lane*16
// (perfectly lane-linear stores; reads are 64B-contiguous per row).
// blocks [0,8192): x tiles (32768); blocks [8192,8448): W tiles (1024)
__global__ void k_quant(const float* __restrict__ x, const float* __restrict__ w,
                        const float* __restrict__ scalars,
                        unsigned char* __restrict__ xq, unsigned char* __restrict__ wq) {
  const int tid = threadIdx.x;
  const int lane = tid & 63;
  const int r = lane & 15;
  const int c = lane >> 4;
  if (blockIdx.x < 8192) {
    float qs = scalars[4], inv = scalars[5];
    int wave = blockIdx.x * 4 + (tid >> 6);   // tile index, 0..32767
    int mb = wave >> 4;
    int kt = wave & 15;
    const float4* src = (const float4*)(x + (size_t)(mb * 16 + r) * Kdim + kt * 64 + c * 16);
    unsigned o[4];
    #pragma unroll
    for (int v = 0; v < 4; ++v) {
      float4 f = src[v];
      o[v] = (unsigned)(qact8(f.x, qs, inv) & 0xff) |
             ((unsigned)(qact8(f.y, qs, inv) & 0xff) << 8) |
             ((unsigned)(qact8(f.z, qs, inv) & 0xff) << 16) |
             ((unsigned)(qact8(f.w, qs, inv) & 0xff) << 24);
    }
    uint4 pk; pk.x = o[0]; pk.y = o[1]; pk.z = o[2]; pk.w = o[3];
    *(uint4*)(xq + (size_t)wave * 1024 + lane * 16) = pk;
  } else {
    float inv_g = scalars[0] + FEPS;
    int wave = (blockIdx.x - 8192) * 4 + (tid >> 6);  // tile index, 0..1023
    int nb = wave >> 4;
    int kt = wave & 15;
    const float4* src = (const float4*)(w + (size_t)(nb * 16 + r) * Kdim + kt * 64 + c * 16);
    unsigned o[4];
    #pragma unroll
    for (int v = 0; v < 4; ++v) {
      float4 f = src[v];
      int a = (int)rintf(fminf(fmaxf(f.x / inv_g, -1.f), 1.f));
      int b = (int)rintf(fminf(fmaxf(f.y / inv_g, -1.f), 1.f));
      int cc = (int)rintf(fminf(fmaxf(f.z / inv_g, -1.f), 1.f));
      int d = (int)rintf(fminf(fmaxf(f.w / inv_g, -1.f), 1.f));
      o[v] = (unsigned)(a & 0xff) | ((unsigned)(b & 0xff) << 8) |
             ((unsigned)(cc & 0xff) << 16) | ((unsigned)(d & 0xff) << 24);
    }
    uint4 pk; pk.x = o[0]; pk.y = o[1]; pk.z = o[2]; pk.w = o[3];
    *(uint4*)(wq + (size_t)wave * 1024 + lane * 16) = pk;
  }
}

// ---------------- pass 4: int8 MFMA GEMM, LDS-staged, counted-vmcnt ---------
// 128x128 tile per block, 4 waves 2x2, BK=64 i8. 3 LDS buffers (16KB each):
// per step: vmcnt(4) -> raw barrier -> ds_read frags -> STAGE(kt+2) -> 16 MFMA
// wrapped in s_setprio(1). LDS layout == fragment layout (1KB tiles, lane*16):
// staging is linear (global_load_lds) and ds_read_b128 is conflict-free.
__launch_bounds__(256)
__global__ void k_gemm(const unsigned char* __restrict__ xq, const unsigned char* __restrict__ wq,
                       const float* __restrict__ scalars, const float* __restrict__ bq,
                       float* __restrict__ out) {
  __shared__ __align__(16) unsigned char lds[3 * 16384];

  const int tid = threadIdx.x;
  const int lane = tid & 63;
  const int wv = tid >> 6;          // 0..3
  const int wr = wv >> 1;           // wave row 0..1
  const int wc = wv & 1;            // wave col 0..1

  // XCD-aware swizzle (2048 % 8 == 0 -> bijective); each XCD owns a contiguous
  // mtile range; consecutive swz share mtile (A-panel L2-hot across its 8 ntiles).
  int bid = blockIdx.x;
  int swz = (bid & 7) * ((int)gridDim.x >> 3) + (bid >> 3);
  const int mtile = swz >> 3;       // 0..255
  const int ntile = swz & 7;        // 0..7
  const int m0 = mtile * 128;
  const int n0 = ntile * 128;

  // per-wave stage pointers: wave wv stages A tiles {wv, wv+4}, B tiles {wv, wv+4}
  const unsigned char* gA0 = xq + ((size_t)(mtile * 8 + wv) * 16) * 1024 + lane * 16;
  const unsigned char* gA1 = xq + ((size_t)(mtile * 8 + wv + 4) * 16) * 1024 + lane * 16;
  const unsigned char* gB0 = wq + ((size_t)(ntile * 8 + wv) * 16) * 1024 + lane * 16;
  const unsigned char* gB1 = wq + ((size_t)(ntile * 8 + wv + 4) * 16) * 1024 + lane * 16;
  const int lA0 = wv * 1024, lA1 = (wv + 4) * 1024;
  const int lB0 = 8192 + wv * 1024, lB1 = 8192 + (wv + 4) * 1024;

#define STAGE(kt, buf) do {                                   \
    unsigned char* base_ = lds + (buf) * 16384;               \
    gload16(gA0 + (size_t)(kt) * 1024, base_ + lA0);          \
    gload16(gA1 + (size_t)(kt) * 1024, base_ + lA1);          \
    gload16(gB0 + (size_t)(kt) * 1024, base_ + lB0);          \
    gload16(gB1 + (size_t)(kt) * 1024, base_ + lB1);          \
  } while (0)

  int4v acc[4][4];
  #pragma unroll
  for (int i = 0; i < 4; ++i)
    #pragma unroll
    for (int j = 0; j < 4; ++j)
      acc[i][j] = (int4v){0, 0, 0, 0};

  const int aoff = wr * 4 * 1024 + lane * 16;
  const int boff = 8192 + wc * 4 * 1024 + lane * 16;

  STAGE(0, 0);
  STAGE(1, 1);

  int cur = 0;
  for (int kt = 0; kt < 15; ++kt) {
    asm volatile("s_waitcnt vmcnt(4)" ::: "memory");  // stage(kt) landed
    __builtin_amdgcn_s_barrier();
    asm volatile("" ::: "memory");                    // pin mem ops below barrier
    const unsigned char* bufp = lds + cur * 16384;
    int4v a[4], b[4];
    #pragma unroll
    for (int mi = 0; mi < 4; ++mi)
      a[mi] = *(const int4v*)(bufp + aoff + mi * 1024);
    #pragma unroll
    for (int ni = 0; ni < 4; ++ni)
      b[ni] = *(const int4v*)(bufp + boff + ni * 1024);
    if (kt < 14) {
      int nb = cur + 2; if (nb >= 3) nb -= 3;
      STAGE(kt + 2, nb);                              // issued post-barrier: no race
    }
    __builtin_amdgcn_s_setprio(1);
    #pragma unroll
    for (int mi = 0; mi < 4; ++mi)
      #pragma unroll
      for (int ni = 0; ni < 4; ++ni)
        acc[mi][ni] = __builtin_amdgcn_mfma_i32_16x16x64_i8(a[mi], b[ni], acc[mi][ni], 0, 0, 0);
    __builtin_amdgcn_s_setprio(0);
    cur = (cur == 2) ? 0 : cur + 1;
  }
  // final step kt=15
  asm volatile("s_waitcnt vmcnt(0)" ::: "memory");
  __builtin_amdgcn_s_barrier();
  asm volatile("" ::: "memory");
  {
    const unsigned char* bufp = lds + cur * 16384;
    int4v a[4], b[4];
    #pragma unroll
    for (int mi = 0; mi < 4; ++mi)
      a[mi] = *(const int4v*)(bufp + aoff + mi * 1024);
    #pragma unroll
    for (int ni = 0; ni < 4; ++ni)
      b[ni] = *(const int4v*)(bufp + boff + ni * 1024);
    __builtin_amdgcn_s_setprio(1);
    #pragma unroll
    for (int mi = 0; mi < 4; ++mi)
      #pragma unroll
      for (int ni = 0; ni < 4; ++ni)
        acc[mi][ni] = __builtin_amdgcn_mfma_i32_16x16x64_i8(a[mi], b[ni], acc[mi][ni], 0, 0, 0);
    __builtin_amdgcn_s_setprio(0);
  }
#undef STAGE

  // epilogue: exact i32 -> f32, scale, bias
  const float sg = scalars[3];
  const int fr = lane & 15;
  #pragma unroll
  for (int ni = 0; ni < 4; ++ni) {
    const int col = n0 + wc * 64 + ni * 16 + fr;
    const float bb = bq[col];
    #pragma unroll
    for (int mi = 0; mi < 4; ++mi) {
      const int rowb = m0 + wr * 64 + mi * 16 + (lane >> 4) * 4;
      #pragma unroll
      for (int r = 0; r < 4; ++r)
        out[(size_t)(rowb + r) * Ndim + col] = (float)acc[mi][ni][r] * sg + bb;
    }
  }
}

extern "C" void kernel_launch(void* const* d_in, const int* in_sizes, int n_in,
                              void* d_out, int out_size, void* d_ws, size_t ws_size,
                              hipStream_t stream) {
  const float* x = (const float*)d_in[0];
  const float* weight = (const float*)d_in[1];
  const float* bias = (const float*)d_in[2];
  float* out = (float*)d_out;

  if (ws_size < WS_NEED) return;

  char* ws = (char*)d_ws;
  float* scalars = (float*)ws;
  float* partials = (float*)(ws + 1024);
  unsigned* pmax = (unsigned*)(ws + 4096);
  float* bq = (float*)(ws + 16384);
  unsigned char* wq = (unsigned char*)(ws + WQ_OFF);
  unsigned char* xq = (unsigned char*)(ws + XQ_OFF);

  k_pre<<<2304, 256, 0, stream>>>((const uint4*)x, (const float4*)weight, pmax, partials);
  k_finalize<<<1, 256, 0, stream>>>(bias, partials, pmax, scalars, bq);
  k_quant<<<8448, 256, 0, stream>>>(x, weight, scalars, xq, wq);
  k_gemm<<<2048, 256, 0, stream>>>(xq, wq, scalars, bq, out);
}

// Round 6
// 95.938 us; speedup vs baseline: 1.2362x; 1.0748x over previous
//
#include <hip/hip_runtime.h>

typedef __attribute__((ext_vector_type(4))) int int4v;

constexpr int Mdim = 32768;   // 8*4096
constexpr int Kdim = 1024;
constexpr int Ndim = 1024;
constexpr float FEPS = 1e-8f;

// ---------------- ws layout (bytes) ----------------
// 0      : float scalars[8]  {gamma_w, gamma_b, scale, sg, qs, inv_scale}
// 1024   : float partials[256]   (|W| partial sums)
// 4096   : unsigned pmax[2048]   (per-block |x| max bits)
// 16384  : float bq[1024]
// 32768  : int8 wq (1 MB)  -- TILED: tile t=(nb*16+kt) is 1KB; byte l*16 of tile t
//                             holds W[nb*16 + (l&15)][kt*64 + (l>>4)*16 .. +15]
constexpr size_t WQ_OFF = 32768;
constexpr size_t WS_NEED = WQ_OFF + (size_t)Ndim * Kdim;

// ---------------- pass 1 (merged): |x| absmax partials + |W| sum partials ----
// blocks [0,2048): absmax of x -> pmax[b]; blocks [2048,2304): |W| sums -> partials[b-2048]
__global__ void k_pre(const uint4* __restrict__ xv, const float4* __restrict__ wv,
                      unsigned* __restrict__ pmax, float* __restrict__ partials) {
  const int tid = threadIdx.x;
  if (blockIdx.x < 2048) {
    int i0 = blockIdx.x * 256 + tid;
    const int stride = 2048 * 256;
    const int n4 = Mdim * Kdim / 4;
    unsigned m = 0u;
    for (int i = i0; i < n4; i += stride) {
      uint4 v = xv[i];
      m = max(m, v.x & 0x7fffffffu);
      m = max(m, v.y & 0x7fffffffu);
      m = max(m, v.z & 0x7fffffffu);
      m = max(m, v.w & 0x7fffffffu);
    }
    #pragma unroll
    for (int off = 32; off > 0; off >>= 1)
      m = max(m, (unsigned)__shfl_down((int)m, off, 64));
    __shared__ unsigned red[4];
    if ((tid & 63) == 0) red[tid >> 6] = m;
    __syncthreads();
    if (tid == 0)
      pmax[blockIdx.x] = max(max(red[0], red[1]), max(red[2], red[3]));
  } else {
    int wb = blockIdx.x - 2048;
    float s = 0.f;
    const int stride = 256 * 256;
    const int n4 = Ndim * Kdim / 4;
    for (int i = wb * 256 + tid; i < n4; i += stride) {
      float4 v = wv[i];
      s += fabsf(v.x) + fabsf(v.y) + fabsf(v.z) + fabsf(v.w);
    }
    __shared__ float red[256];
    red[tid] = s;
    __syncthreads();
    for (int h = 128; h > 0; h >>= 1) {
      if (tid < h) red[tid] += red[tid + h];
      __syncthreads();
    }
    if (tid == 0) partials[wb] = red[0];
  }
}

// ---------------- pass 2: scalars + bias quant + W quant (256 blocks) --------
// Every block reduces partials[256] locally -> gamma_w, then ternary-quantizes
// its 4 W-tiles into the tiled wq layout. Block 0 additionally computes
// scalars[] and bq[] (identical math to prior rounds).
__global__ void k_finalize2(const float* __restrict__ bias, const float* __restrict__ w,
                            const float* __restrict__ partials, const unsigned* __restrict__ pmax,
                            float* __restrict__ scalars, float* __restrict__ bq,
                            unsigned char* __restrict__ wq) {
  __shared__ float red[256];
  const int t = threadIdx.x;
  const int b = blockIdx.x;

  // local gamma_w from the 256 fixed partials
  red[t] = partials[t];
  __syncthreads();
  for (int h = 128; h > 0; h >>= 1) {
    if (t < h) red[t] += red[t + h];
    __syncthreads();
  }
  const float gw = red[0] / (1024.0f * 1024.0f);
  __syncthreads();
  const float inv_g = gw + FEPS;

  // quantize 4 W tiles: tile = b*4 + (t>>6); coalesced read, permuted write
  {
    const int tile = b * 4 + (t >> 6);   // 0..1023
    const int nb = tile >> 4;
    const int kt = tile & 15;
    const int l = t & 63;
    const float4* src = (const float4*)(w + (size_t)(nb * 16 + (l >> 2)) * Kdim + kt * 64 + (l & 3) * 16);
    unsigned o[4];
    #pragma unroll
    for (int v = 0; v < 4; ++v) {
      float4 f = src[v];
      int a  = (int)rintf(fminf(fmaxf(f.x / inv_g, -1.f), 1.f));
      int bb = (int)rintf(fminf(fmaxf(f.y / inv_g, -1.f), 1.f));
      int cc = (int)rintf(fminf(fmaxf(f.z / inv_g, -1.f), 1.f));
      int dd = (int)rintf(fminf(fmaxf(f.w / inv_g, -1.f), 1.f));
      o[v] = (unsigned)(a & 0xff) | ((unsigned)(bb & 0xff) << 8) |
             ((unsigned)(cc & 0xff) << 16) | ((unsigned)(dd & 0xff) << 24);
    }
    uint4 pk; pk.x = o[0]; pk.y = o[1]; pk.z = o[2]; pk.w = o[3];
    const int lp = (l >> 2) | ((l & 3) << 4);   // fragment lane
    *(uint4*)(wq + (size_t)tile * 1024 + lp * 16) = pk;
  }

  if (b != 0) return;

  // block 0: absmax reduce + scalars + bq
  __shared__ unsigned redu[256];
  __shared__ float sh_gb;
  unsigned m = 0u;
  #pragma unroll
  for (int i = 0; i < 8; ++i) m = max(m, pmax[t + 256 * i]);
  redu[t] = m;
  float s = fabsf(bias[t]) + fabsf(bias[t + 256]) + fabsf(bias[t + 512]) + fabsf(bias[t + 768]);
  red[t] = s;
  __syncthreads();
  for (int h = 128; h > 0; h >>= 1) {
    if (t < h) {
      red[t] += red[t + h];
      redu[t] = max(redu[t], redu[t + h]);
    }
    __syncthreads();
  }
  if (t == 0) {
    float gb = red[0] / 1024.0f;
    float maxval = __uint_as_float(redu[0]);
    float v = maxval / 127.0f + FEPS;
    int e = (int)((__float_as_uint(v) >> 23) & 0xff) - 127;
    float scale = ldexpf(1.0f, e);
    scalars[0] = gw;
    scalars[1] = gb;
    scalars[2] = scale;
    scalars[3] = scale * gw;       // epilogue multiplier
    scalars[4] = 127.0f * scale;   // clip bound (exact)
    scalars[5] = ldexpf(1.0f, -e); // inv_scale (exact power of 2)
    sh_gb = gb;
  }
  __syncthreads();
  float gb = sh_gb;
  for (int i = t; i < 1024; i += 256) {
    float q = rintf(bias[i] / (gb + FEPS));
    q = fminf(fmaxf(q, -1.0f), 1.0f);
    bq[i] = q * gb;
  }
}

// ---------------- pass 3: fused quant + int8 MFMA GEMM ----------------------
// One block per mtile (128 rows), 16 waves. Phase A: quantize this block's
// 128x1024 fp32 x-panel into LDS (fragment-tiled int8, 128 KB), one barrier.
// Phase B: barrier-free K-loop; A-frags from LDS (linear ds_read_b128,
// conflict-free), B-frags direct global->VGPR from L2-resident tiled wq.
// Wave (wr=wv>>2, wc=wv&3) owns rows wr*32+[0,32), cols wc*64 within each
// 256-col ntile-pair; outer loop np=0..3 covers the 1024 output cols.
__launch_bounds__(1024)
__global__ void k_megagemm(const float* __restrict__ x, const unsigned char* __restrict__ wq,
                           const float* __restrict__ scalars, const float* __restrict__ bq,
                           float* __restrict__ out) {
  __shared__ __align__(16) unsigned char Alds[131072];   // 128 tiles x 1KB

  const int tid = threadIdx.x;
  const int lane = tid & 63;
  const int wv = tid >> 6;          // 0..15
  const int mtile = blockIdx.x;     // 0..255
  const float qs = scalars[4], inv = scalars[5];

  // ---- Phase A: quantize 8 tiles per wave into LDS ----
  #pragma unroll
  for (int i = 0; i < 8; ++i) {
    const int tile = wv * 8 + i;    // 0..127
    const int mb = tile >> 4;
    const int kt = tile & 15;
    const float4* src = (const float4*)(x + (size_t)(mtile * 128 + mb * 16 + (lane >> 2)) * Kdim
                                          + kt * 64 + (lane & 3) * 16);
    unsigned o[4];
    #pragma unroll
    for (int v = 0; v < 4; ++v) {
      float4 f = src[v];
      int a = (int)rintf(fminf(fmaxf(f.x, -qs), qs) * inv);
      int b = (int)rintf(fminf(fmaxf(f.y, -qs), qs) * inv);
      int c = (int)rintf(fminf(fmaxf(f.z, -qs), qs) * inv);
      int d = (int)rintf(fminf(fmaxf(f.w, -qs), qs) * inv);
      o[v] = (unsigned)(a & 0xff) | ((unsigned)(b & 0xff) << 8) |
             ((unsigned)(c & 0xff) << 16) | ((unsigned)(d & 0xff) << 24);
    }
    uint4 pk; pk.x = o[0]; pk.y = o[1]; pk.z = o[2]; pk.w = o[3];
    const int lp = (lane >> 2) | ((lane & 3) << 4);   // fragment lane
    *(uint4*)(Alds + (size_t)tile * 1024 + lp * 16) = pk;
  }
  __syncthreads();   // the only barrier; Alds is read-only below

  // ---- Phase B: GEMM ----
  const int wr = wv >> 2;           // 0..3 : rows wr*32
  const int wc = wv & 3;            // 0..3 : cols wc*64 (within 256-wide pair)
  const float sg = scalars[3];
  const unsigned char* Alds_a0 = Alds + (size_t)(wr * 2) * 16 * 1024 + lane * 16;
  const unsigned char* Alds_a1 = Alds + (size_t)(wr * 2 + 1) * 16 * 1024 + lane * 16;

  for (int np = 0; np < 4; ++np) {
    int4v acc[2][4];
    #pragma unroll
    for (int i = 0; i < 2; ++i)
      #pragma unroll
      for (int j = 0; j < 4; ++j)
        acc[i][j] = (int4v){0, 0, 0, 0};

    const unsigned char* Bb = wq + ((size_t)(np * 16 + wc * 4) * 16) * 1024 + lane * 16;

    #pragma unroll
    for (int kt = 0; kt < 16; ++kt) {
      int4v b0 = *(const int4v*)(Bb + (size_t)(0 * 16 + kt) * 1024);
      int4v b1 = *(const int4v*)(Bb + (size_t)(1 * 16 + kt) * 1024);
      int4v b2 = *(const int4v*)(Bb + (size_t)(2 * 16 + kt) * 1024);
      int4v b3 = *(const int4v*)(Bb + (size_t)(3 * 16 + kt) * 1024);
      int4v a0 = *(const int4v*)(Alds_a0 + (size_t)kt * 1024);
      int4v a1 = *(const int4v*)(Alds_a1 + (size_t)kt * 1024);
      acc[0][0] = __builtin_amdgcn_mfma_i32_16x16x64_i8(a0, b0, acc[0][0], 0, 0, 0);
      acc[0][1] = __builtin_amdgcn_mfma_i32_16x16x64_i8(a0, b1, acc[0][1], 0, 0, 0);
      acc[0][2] = __builtin_amdgcn_mfma_i32_16x16x64_i8(a0, b2, acc[0][2], 0, 0, 0);
      acc[0][3] = __builtin_amdgcn_mfma_i32_16x16x64_i8(a0, b3, acc[0][3], 0, 0, 0);
      acc[1][0] = __builtin_amdgcn_mfma_i32_16x16x64_i8(a1, b0, acc[1][0], 0, 0, 0);
      acc[1][1] = __builtin_amdgcn_mfma_i32_16x16x64_i8(a1, b1, acc[1][1], 0, 0, 0);
      acc[1][2] = __builtin_amdgcn_mfma_i32_16x16x64_i8(a1, b2, acc[1][2], 0, 0, 0);
      acc[1][3] = __builtin_amdgcn_mfma_i32_16x16x64_i8(a1, b3, acc[1][3], 0, 0, 0);
    }

    // epilogue for this ntile-pair (writes overlap next pair's compute)
    #pragma unroll
    for (int ni = 0; ni < 4; ++ni) {
      const int col = np * 256 + wc * 64 + ni * 16 + (lane & 15);
      const float bb = bq[col];
      #pragma unroll
      for (int mi = 0; mi < 2; ++mi) {
        const int rowb = mtile * 128 + wr * 32 + mi * 16 + (lane >> 4) * 4;
        #pragma unroll
        for (int r = 0; r < 4; ++r)
          out[(size_t)(rowb + r) * Ndim + col] = (float)acc[mi][ni][r] * sg + bb;
      }
    }
  }
}

extern "C" void kernel_launch(void* const* d_in, const int* in_sizes, int n_in,
                              void* d_out, int out_size, void* d_ws, size_t ws_size,
                              hipStream_t stream) {
  const float* x = (const float*)d_in[0];
  const float* weight = (const float*)d_in[1];
  const float* bias = (const float*)d_in[2];
  float* out = (float*)d_out;

  if (ws_size < WS_NEED) return;

  char* ws = (char*)d_ws;
  float* scalars = (float*)ws;
  float* partials = (float*)(ws + 1024);
  unsigned* pmax = (unsigned*)(ws + 4096);
  float* bq = (float*)(ws + 16384);
  unsigned char* wq = (unsigned char*)(ws + WQ_OFF);

  k_pre<<<2304, 256, 0, stream>>>((const uint4*)x, (const float4*)weight, pmax, partials);
  k_finalize2<<<256, 256, 0, stream>>>(bias, weight, partials, pmax, scalars, bq, wq);
  k_megagemm<<<256, 1024, 0, stream>>>(x, wq, scalars, bq, out);
}